// Round 2
// baseline (893.405 us; speedup 1.0000x reference)
//
#include <hip/hip_runtime.h>
#include <hip/hip_bf16.h>
#include <cstdint>

// Problem constants
#define B_   8
#define L_   2048
#define E_   1024
#define H_   16
#define D_   64
#define M_   (B_ * L_)     // 16384 rows for the big GEMMs
#define EPS_ 1e-6f
#define SEG  8             // L-segments for partial KV accumulation (4 -> 8: 1024 blocks = 4/CU)
#define LSEG (L_ / SEG)    // 256
#define CH   32            // l-rows per LDS chunk
#define KSTR 272           // kf4s LDS row stride in bf16 (pad 256->272: b128-store banks spread)
#define VSTR 68            // vs LDS row stride in fp32 (pad 64->68)

typedef __bf16 bf16;
typedef __bf16 bf16x8 __attribute__((ext_vector_type(8)));
typedef __bf16 bf16x4 __attribute__((ext_vector_type(4)));
typedef float  floatx4 __attribute__((ext_vector_type(4)));

// ---------------------------------------------------------------------------
// async global->LDS, 16B per lane (dest = wave-uniform base + lane*16)
// ---------------------------------------------------------------------------
__device__ inline void async_cp16(const void* g, void* l) {
  __builtin_amdgcn_global_load_lds(
      (__attribute__((address_space(1))) void*)const_cast<void*>(g),
      (__attribute__((address_space(3))) void*)l,
      16, 0, 0);
}

// ---------------------------------------------------------------------------
// K1: fp32 -> bf16 elementwise convert (query -> Xbf), 8 elems/thread
// ---------------------------------------------------------------------------
__global__ __launch_bounds__(256) void k_convert_x(const float* __restrict__ x,
                                                   bf16* __restrict__ o) {
  size_t i = ((size_t)blockIdx.x * 256 + threadIdx.x) * 8;
  floatx4 a = *(const floatx4*)(x + i);
  floatx4 b = *(const floatx4*)(x + i + 4);
  bf16x8 r;
  r[0] = (bf16)a[0]; r[1] = (bf16)a[1]; r[2] = (bf16)a[2]; r[3] = (bf16)a[3];
  r[4] = (bf16)b[0]; r[5] = (bf16)b[1]; r[6] = (bf16)b[2]; r[7] = (bf16)b[3];
  *(bf16x8*)(o + i) = r;
}

// ---------------------------------------------------------------------------
// K2: transpose 4 weight matrices (E x E fp32, (in,out)) -> bf16 (out,in)
// ---------------------------------------------------------------------------
struct TArgs { const float* src[4]; bf16* dst[4]; };

__global__ __launch_bounds__(256) void k_transpose_w(TArgs t) {
  __shared__ float tile[32][33];
  const float* src = t.src[blockIdx.z];
  bf16* dst = t.dst[blockIdx.z];
  int bx = blockIdx.x, by = blockIdx.y;
  int x = threadIdx.x, y = threadIdx.y;  // (32, 8)
#pragma unroll
  for (int i = 0; i < 4; i++) {
    int r = by * 32 + y + i * 8;
    tile[y + i * 8][x] = src[(size_t)r * E_ + bx * 32 + x];
  }
  __syncthreads();
#pragma unroll
  for (int i = 0; i < 4; i++) {
    int r = bx * 32 + y + i * 8;
    dst[(size_t)r * E_ + by * 32 + x] = (bf16)tile[x][y + i * 8];
  }
}

// ---------------------------------------------------------------------------
// K3/K7: bf16 MFMA GEMM (m97 "gemm_bt" structure), unchanged from round 1.
// ---------------------------------------------------------------------------
struct GemmArgs {
  const bf16*  Bt[3];
  const float* bias[3];
  void*        C[3];
  int          obf[3];   // 1 = bf16 output, 0 = fp32 output
};

__global__ __launch_bounds__(256) void k_gemm_bt(const bf16* __restrict__ A,
                                                 GemmArgs g, int Kd, int Nd) {
  __shared__ __attribute__((aligned(16))) bf16 As[128 * 32];
  __shared__ __attribute__((aligned(16))) bf16 Bs[128 * 32];
  const int z = blockIdx.z;
  const bf16*  Bt   = g.Bt[z];
  const float* bias = g.bias[z];

  const int tid  = threadIdx.x;
  const int wid  = tid >> 6;
  const int lane = tid & 63;
  const int quad = lane >> 4;
  const int l15  = lane & 15;
  const int wm   = wid >> 1, wn = wid & 1;
  const int bm   = blockIdx.y, bn = blockIdx.x;

  const bf16* ga0 = A  + (size_t)(bm * 128 + wid * 32 + (lane >> 2)) * Kd + (lane & 3) * 8;
  const bf16* ga1 = ga0 + (size_t)16 * Kd;
  const bf16* gb0 = Bt + (size_t)(bn * 128 + wid * 32 + (lane >> 2)) * Kd + (lane & 3) * 8;
  const bf16* gb1 = gb0 + (size_t)16 * Kd;
  bf16* la = &As[wid * 1024];
  bf16* lb = &Bs[wid * 1024];

  floatx4 acc[4][4] = {};

  for (int kk = 0; kk < Kd; kk += 32) {
    async_cp16(ga0, la);        async_cp16(ga1, la + 512);
    async_cp16(gb0, lb);        async_cp16(gb1, lb + 512);
    ga0 += 32; ga1 += 32; gb0 += 32; gb1 += 32;
    __syncthreads();

    bf16x8 af[4], bfm[4];
#pragma unroll
    for (int i = 0; i < 4; i++)
      af[i] = *(const bf16x8*)&As[(wm * 64 + i * 16 + l15) * 32 + quad * 8];
#pragma unroll
    for (int i = 0; i < 4; i++)
      bfm[i] = *(const bf16x8*)&Bs[(wn * 64 + i * 16 + l15) * 32 + quad * 8];
#pragma unroll
    for (int i = 0; i < 4; i++)
#pragma unroll
      for (int j = 0; j < 4; j++)
        acc[i][j] = __builtin_amdgcn_mfma_f32_16x16x32_bf16(af[i], bfm[j], acc[i][j], 0, 0, 0);
    __syncthreads();
  }

  const int colb = bn * 128 + wn * 64 + l15;
  const int rowb = bm * 128 + wm * 64 + quad * 4;
  if (g.obf[z]) {
    bf16* C = (bf16*)g.C[z];
#pragma unroll
    for (int i = 0; i < 4; i++)
#pragma unroll
      for (int j = 0; j < 4; j++) {
        int col = colb + j * 16;
        float bv = bias[col];
#pragma unroll
        for (int r = 0; r < 4; r++) {
          int row = rowb + i * 16 + r;
          C[(size_t)row * Nd + col] = (bf16)(acc[i][j][r] + bv);
        }
      }
  } else {
    float* C = (float*)g.C[z];
#pragma unroll
    for (int i = 0; i < 4; i++)
#pragma unroll
      for (int j = 0; j < 4; j++) {
        int col = colb + j * 16;
        float bv = bias[col];
#pragma unroll
        for (int r = 0; r < 4; r++) {
          int row = rowb + i * 16 + r;
          C[(size_t)row * Nd + col] = acc[i][j][r] + bv;
        }
      }
  }
}

// ---------------------------------------------------------------------------
// K4: fused k-softmax + features + partial KV & ksum. Round-2 rework:
//  - SEG 4->8 (grid 1024 = 4 blocks/CU), chunk 64->32 rows (LDS 48->25.5 KB)
//  - phase-A stores vectorized to b128 with padded strides (was 16-way-conflict
//    scalar b16: SQ_LDS_BANK_CONFLICT 2.62M cycles at 23% occupancy)
//  - segs 4..7 partials + all ksum partials live in d_out (scratch until K7)
// ---------------------------------------------------------------------------
__global__ __launch_bounds__(256) void k_kv_partial(const float* __restrict__ Kf,
                                                    const bf16* __restrict__ Vb,
                                                    float* __restrict__ kvpA,
                                                    float* __restrict__ kvpB,
                                                    float* __restrict__ ksp) {
  const int bh  = blockIdx.x;        // 0..127
  const int seg = blockIdx.y;        // 0..SEG-1
  const int b = bh >> 4, h = bh & 15;
  const int t = threadIdx.x;
  __shared__ __attribute__((aligned(16))) bf16  kf4s[CH * KSTR];  // 17,408 B
  __shared__ __attribute__((aligned(16))) float vs[CH * VSTR];    //  8,704 B

  float acc[64];
#pragma unroll
  for (int i = 0; i < 64; i++) acc[i] = 0.f;
  float ks = 0.f;

  const int row = t >> 3, sub = t & 7;  // 8 lanes per l-row in phase A

  for (int c = 0; c < LSEG / CH; c++) {
    const int l = seg * LSEG + c * CH + row;
    // ---- phase A: softmax + features into LDS (vectorized stores) ----
    const float* kp = Kf + ((size_t)(b * L_ + l) * E_ + h * 64 + sub * 8);
    floatx4 xv0 = *(const floatx4*)kp;
    floatx4 xv1 = *(const floatx4*)(kp + 4);
    float mx = -1e30f;
#pragma unroll
    for (int j = 0; j < 4; j++) { mx = fmaxf(mx, xv0[j]); mx = fmaxf(mx, xv1[j]); }
    mx = fmaxf(mx, __shfl_xor(mx, 1));
    mx = fmaxf(mx, __shfl_xor(mx, 2));
    mx = fmaxf(mx, __shfl_xor(mx, 4));
    float ev[8]; float s = 0.f;
#pragma unroll
    for (int j = 0; j < 4; j++) { ev[j]     = __expf(xv0[j] - mx); s += ev[j]; }
#pragma unroll
    for (int j = 0; j < 4; j++) { ev[4 + j] = __expf(xv1[j] - mx); s += ev[4 + j]; }
    s += __shfl_xor(s, 1); s += __shfl_xor(s, 2); s += __shfl_xor(s, 4);
    const float inv = 1.f / s;
    const float ang = 1.57079632679f * (float)(l + 1) / (float)L_;
    const float sn = __sinf(ang), cs = __cosf(ang);
    bf16x8 w0, w1, w2, w3;
#pragma unroll
    for (int i = 0; i < 8; i++) {
      const float p = ev[i] * inv;
      w0[i] = (bf16)(p * sn);
      w1[i] = (bf16)(p * cs);
      w2[i] = (bf16)((1.f - p) * sn);
      w3[i] = (bf16)((1.f - p) * cs);
    }
    bf16* kb = &kf4s[row * KSTR + sub * 8];
    *(bf16x8*)(kb)       = w0;
    *(bf16x8*)(kb + 64)  = w1;
    *(bf16x8*)(kb + 128) = w2;
    *(bf16x8*)(kb + 192) = w3;
    // stage V row slice as fp32 (cvt once here, not per-FMA in phase B)
    const bf16* vp = Vb + ((size_t)(b * L_ + l) * E_ + h * 64 + sub * 8);
    bf16x8 v0 = *(const bf16x8*)vp;
    floatx4 vf0, vf1;
#pragma unroll
    for (int i = 0; i < 4; i++) { vf0[i] = (float)v0[i]; vf1[i] = (float)v0[4 + i]; }
    *(floatx4*)&vs[row * VSTR + sub * 8]     = vf0;
    *(floatx4*)&vs[row * VSTR + sub * 8 + 4] = vf1;
    __syncthreads();

    // ---- phase B: rank-1 accumulate KV[f][*] += kf4[l][f] * v[l][*] ----
#pragma unroll 2
    for (int ll = 0; ll < CH; ll++) {
      const float af = (float)kf4s[ll * KSTR + t];
      ks += af;
#pragma unroll
      for (int d4 = 0; d4 < 16; d4++) {
        floatx4 vv = *(const floatx4*)&vs[ll * VSTR + d4 * 4];  // wave-uniform broadcast
        acc[d4 * 4 + 0] += af * vv[0];
        acc[d4 * 4 + 1] += af * vv[1];
        acc[d4 * 4 + 2] += af * vv[2];
        acc[d4 * 4 + 3] += af * vv[3];
      }
    }
    __syncthreads();
  }

  float* kvp = (seg < 4) ? kvpA : kvpB;
  const int sg = seg & 3;
  const size_t base = ((size_t)(sg * 128 + bh) * 256 + t) * 64;
#pragma unroll
  for (int d4 = 0; d4 < 16; d4++) {
    floatx4 o; o[0] = acc[d4*4+0]; o[1] = acc[d4*4+1]; o[2] = acc[d4*4+2]; o[3] = acc[d4*4+3];
    *(floatx4*)&kvp[base + d4 * 4] = o;
  }
  ksp[(seg * 128 + bh) * 256 + t] = ks;
}

// ---------------------------------------------------------------------------
// K5: reduce 8 partials (4 from ws, 4 from d_out) -> KVb bf16 + ksum fp32
// ---------------------------------------------------------------------------
__global__ __launch_bounds__(256) void k_kv_reduce(const float* __restrict__ kvpA,
                                                   const float* __restrict__ kvpB,
                                                   const float* __restrict__ ksp,
                                                   bf16* __restrict__ KVb,
                                                   float* __restrict__ ksum) {
  const int bh = blockIdx.x;
  const int f  = threadIdx.x;
  const size_t o = ((size_t)bh * 256 + f) * 64;
#pragma unroll 4
  for (int d4 = 0; d4 < 16; d4++) {
    floatx4 s = {0.f, 0.f, 0.f, 0.f};
    for (int g = 0; g < 4; g++) {
      s += *(const floatx4*)&kvpA[((size_t)(g * 128 + bh) * 256 + f) * 64 + d4 * 4];
      s += *(const floatx4*)&kvpB[((size_t)(g * 128 + bh) * 256 + f) * 64 + d4 * 4];
    }
    bf16x4 r; r[0] = (bf16)s[0]; r[1] = (bf16)s[1]; r[2] = (bf16)s[2]; r[3] = (bf16)s[3];
    *(bf16x4*)&KVb[o + d4 * 4] = r;
  }
  float ss = 0.f;
  for (int g = 0; g < SEG; g++) ss += ksp[(g * 128 + bh) * 256 + f];
  ksum[bh * 256 + f] = ss;
}

// ---------------------------------------------------------------------------
// K6: fused q-softmax + z + (z-scaled qf4) @ KV -> attn rows (l*B+b, E) bf16.
// ---------------------------------------------------------------------------
__global__ __launch_bounds__(256) void k_attn_out(const float* __restrict__ Qf,
                                                  const bf16* __restrict__ KVb,
                                                  const float* __restrict__ ksum,
                                                  bf16* __restrict__ attn) {
  const int lc = blockIdx.x;   // 0..63 (chunks of 32 rows)
  const int bh = blockIdx.y;
  const int b = bh >> 4, h = bh & 15;
  const int t = threadIdx.x;
  __shared__ __attribute__((aligned(16))) float qs4[32 * 256];  // 32 KB
  __shared__ __attribute__((aligned(16))) bf16  kvs[256 * 64];  // 32 KB

  // phase 0: KV -> LDS (row f = t)
  {
    const bf16* src = KVb + (size_t)bh * 256 * 64 + (size_t)t * 64;
    bf16* dst = &kvs[t * 64];
#pragma unroll
    for (int i = 0; i < 8; i++) *(bf16x8*)(dst + i * 8) = *(const bf16x8*)(src + i * 8);
  }

  // phase 1: softmax + z + scaled features (8 lanes per l-row)
  const int row = t >> 3, sub = t & 7;
  const int l = lc * 32 + row;
  const float* qp = Qf + ((size_t)(b * L_ + l) * E_ + h * 64 + sub * 8);
  floatx4 xv0 = *(const floatx4*)qp;
  floatx4 xv1 = *(const floatx4*)(qp + 4);
  float mx = -1e30f;
#pragma unroll
  for (int j = 0; j < 4; j++) { mx = fmaxf(mx, xv0[j]); mx = fmaxf(mx, xv1[j]); }
  mx = fmaxf(mx, __shfl_xor(mx, 1));
  mx = fmaxf(mx, __shfl_xor(mx, 2));
  mx = fmaxf(mx, __shfl_xor(mx, 4));
  float ev[8]; float s = 0.f;
#pragma unroll
  for (int j = 0; j < 4; j++) { ev[j]     = __expf(xv0[j] - mx); s += ev[j]; }
#pragma unroll
  for (int j = 0; j < 4; j++) { ev[4 + j] = __expf(xv1[j] - mx); s += ev[4 + j]; }
  s += __shfl_xor(s, 1); s += __shfl_xor(s, 2); s += __shfl_xor(s, 4);
  const float inv = 1.f / s;

  const float* kb = ksum + bh * 256;
  float s1 = 0.f, s2 = 0.f, s3 = 0.f, s4 = 0.f, t3 = 0.f, t4 = 0.f;
  float p[8];
#pragma unroll
  for (int i = 0; i < 8; i++) {
    const int d = sub * 8 + i;
    p[i] = ev[i] * inv;
    const float k1 = kb[d], k2 = kb[64 + d], k3 = kb[128 + d], k4 = kb[192 + d];
    s1 += p[i] * k1; s2 += p[i] * k2; s3 += p[i] * k3; s4 += p[i] * k4;
    t3 += k3; t4 += k4;
  }
  s1 += __shfl_xor(s1, 1); s1 += __shfl_xor(s1, 2); s1 += __shfl_xor(s1, 4);
  s2 += __shfl_xor(s2, 1); s2 += __shfl_xor(s2, 2); s2 += __shfl_xor(s2, 4);
  s3 += __shfl_xor(s3, 1); s3 += __shfl_xor(s3, 2); s3 += __shfl_xor(s3, 4);
  s4 += __shfl_xor(s4, 1); s4 += __shfl_xor(s4, 2); s4 += __shfl_xor(s4, 4);
  t3 += __shfl_xor(t3, 1); t3 += __shfl_xor(t3, 2); t3 += __shfl_xor(t3, 4);
  t4 += __shfl_xor(t4, 1); t4 += __shfl_xor(t4, 2); t4 += __shfl_xor(t4, 4);

  const float ang = 1.57079632679f * (float)(l + 1) / (float)L_;
  const float sn = __sinf(ang), cs = __cosf(ang);
  const float den1 = sn * s1 + cs * s2;
  const float den2 = sn * (t3 - s3) + cs * (t4 - s4);
  const float z1 = 1.f / fmaxf(den1, EPS_);
  const float z2 = 1.f / fmaxf(den2, EPS_);
#pragma unroll
  for (int i = 0; i < 8; i++) {
    const int d = sub * 8 + i;
    qs4[row * 256 + d]       = z1 * sn * p[i];
    qs4[row * 256 + 64 + d]  = z1 * cs * p[i];
    qs4[row * 256 + 128 + d] = z2 * sn * (1.f - p[i]);
    qs4[row * 256 + 192 + d] = z2 * cs * (1.f - p[i]);
  }
  __syncthreads();

  // phase 2: out[l][d] = sum_f qs4[l][f] * KV[f][d]; thread = 2 l's x 4 d's
  const int lg = t >> 4, dg = t & 15;
  const float* q0 = &qs4[(lg * 2) * 256];
  const float* q1 = &qs4[(lg * 2 + 1) * 256];
  floatx4 a0 = {0.f, 0.f, 0.f, 0.f}, a1 = {0.f, 0.f, 0.f, 0.f};
#pragma unroll 8
  for (int f = 0; f < 256; f++) {
    const float c0 = q0[f], c1 = q1[f];
    bf16x4 kq = *(const bf16x4*)&kvs[f * 64 + dg * 4];
    floatx4 kf; kf[0] = (float)kq[0]; kf[1] = (float)kq[1]; kf[2] = (float)kq[2]; kf[3] = (float)kq[3];
    a0 += c0 * kf;
    a1 += c1 * kf;
  }
  const int l0 = lc * 32 + lg * 2;
#pragma unroll
  for (int li = 0; li < 2; li++) {
    floatx4 a = li ? a1 : a0;
    bf16x4 r; r[0] = (bf16)a[0]; r[1] = (bf16)a[1]; r[2] = (bf16)a[2]; r[3] = (bf16)a[3];
    const size_t rowg = (size_t)(l0 + li) * B_ + b;
    *(bf16x4*)&attn[rowg * E_ + h * 64 + dg * 4] = r;
  }
}

// ---------------------------------------------------------------------------
// Workspace layout (bytes) — identical footprint to round 1 (<= 248,119,296):
// ---------------------------------------------------------------------------
#define WS_XBF  ((size_t)0)           // 33,554,432  bf16 X (attn overlays after QKV gemm)
#define WS_WT   ((size_t)33554432)    //  8,388,608  bf16 W^T x4 (q,k,v,o)
#define WS_QF   ((size_t)41943040)    // 67,108,864  fp32 Q
#define WS_KF   ((size_t)109051904)   // 67,108,864  fp32 K
#define WS_VB   ((size_t)176160768)   // 33,554,432  bf16 V
#define WS_KVPA ((size_t)209715200)   // 33,554,432  fp32 KV partials segs 0..3
#define WS_KVB  ((size_t)243793920)   //  4,194,304  bf16 KV
#define WS_KSUM ((size_t)247988224)   //    131,072  fp32 ksum
#define WS_ATTN WS_XBF
// d_out scratch (67 MB fp32, free until K7 overwrites all of it):
#define DO_KVPB ((size_t)0)           // 33,554,432  fp32 KV partials segs 4..7
#define DO_KSP  ((size_t)33554432)    //  1,048,576  fp32 ksum partials (8 segs)

extern "C" void kernel_launch(void* const* d_in, const int* in_sizes, int n_in,
                              void* d_out, int out_size, void* d_ws, size_t ws_size,
                              hipStream_t stream) {
  (void)in_sizes; (void)n_in; (void)out_size; (void)ws_size;
  const float* query = (const float*)d_in[0];
  const float* Wq = (const float*)d_in[1];
  const float* bq = (const float*)d_in[2];
  const float* Wk = (const float*)d_in[3];
  const float* bk = (const float*)d_in[4];
  const float* Wv = (const float*)d_in[5];
  const float* bv = (const float*)d_in[6];
  const float* Wo = (const float*)d_in[7];
  const float* bo = (const float*)d_in[8];

  char* ws = (char*)d_ws;
  char* dob = (char*)d_out;
  bf16*  Xbf  = (bf16*)(ws + WS_XBF);
  bf16*  Wt   = (bf16*)(ws + WS_WT);
  float* Qf   = (float*)(ws + WS_QF);
  float* Kf   = (float*)(ws + WS_KF);
  bf16*  Vb   = (bf16*)(ws + WS_VB);
  float* kvpA = (float*)(ws + WS_KVPA);
  float* kvpB = (float*)(dob + DO_KVPB);
  float* ksp  = (float*)(dob + DO_KSP);
  bf16*  KVb  = (bf16*)(ws + WS_KVB);
  float* ksum = (float*)(ws + WS_KSUM);
  bf16*  attnb = (bf16*)(ws + WS_ATTN);

  // 1) X -> bf16
  k_convert_x<<<(M_ * E_) / (256 * 8), 256, 0, stream>>>(query, Xbf);

  // 2) W^T -> bf16 (N,K) for all four weights
  TArgs ta;
  ta.src[0] = Wq; ta.src[1] = Wk; ta.src[2] = Wv; ta.src[3] = Wo;
  ta.dst[0] = Wt;                ta.dst[1] = Wt + (size_t)E_ * E_;
  ta.dst[2] = Wt + (size_t)2 * E_ * E_; ta.dst[3] = Wt + (size_t)3 * E_ * E_;
  k_transpose_w<<<dim3(32, 32, 4), dim3(32, 8), 0, stream>>>(ta);

  // 3) batched QKV GEMM (z = 0,1,2): Q,K fp32 out; V bf16 out
  GemmArgs gq;
  gq.Bt[0] = Wt;                       gq.bias[0] = bq; gq.C[0] = Qf; gq.obf[0] = 0;
  gq.Bt[1] = Wt + (size_t)E_ * E_;     gq.bias[1] = bk; gq.C[1] = Kf; gq.obf[1] = 0;
  gq.Bt[2] = Wt + (size_t)2 * E_ * E_; gq.bias[2] = bv; gq.C[2] = Vb; gq.obf[2] = 1;
  k_gemm_bt<<<dim3(E_ / 128, M_ / 128, 3), 256, 0, stream>>>(Xbf, gq, E_, E_);

  // 4) partial KV + ksum (k-softmax fused)
  k_kv_partial<<<dim3(128, SEG), 256, 0, stream>>>(Kf, Vb, kvpA, kvpB, ksp);

  // 5) reduce partials
  k_kv_reduce<<<128, 256, 0, stream>>>(kvpA, kvpB, ksp, KVb, ksum);

  // 6) q-softmax + z + attn (writes (l*B+b)-ordered rows)
  k_attn_out<<<dim3(L_ / 32, 128), 256, 0, stream>>>(Qf, KVb, ksum, attnb);

  // 7) final projection -> d_out (fp32); flat layout already matches reference
  GemmArgs go;
  go.Bt[0] = Wt + (size_t)3 * E_ * E_; go.bias[0] = bo; go.C[0] = d_out; go.obf[0] = 0;
  go.Bt[1] = go.Bt[0]; go.bias[1] = bo; go.C[1] = d_out; go.obf[1] = 0;
  go.Bt[2] = go.Bt[0]; go.bias[2] = bo; go.C[2] = d_out; go.obf[2] = 0;
  k_gemm_bt<<<dim3(E_ / 128, M_ / 128, 1), 256, 0, stream>>>(attnb, go, E_, E_);
}

// Round 3
// 469.429 us; speedup vs baseline: 1.9032x; 1.9032x over previous
//
#include <hip/hip_runtime.h>
#include <hip/hip_bf16.h>
#include <cstdint>

// Problem constants
#define B_   8
#define L_   2048
#define E_   1024
#define H_   16
#define D_   64
#define M_   (B_ * L_)
#define EPS_ 1e-6f
#define PI2_ 1.57079632679f

typedef __bf16 bf16;
typedef __bf16 bf16x8 __attribute__((ext_vector_type(8)));
typedef __bf16 bf16x4 __attribute__((ext_vector_type(4)));
typedef float  floatx4 __attribute__((ext_vector_type(4)));

__device__ inline void async_cp16(const void* g, void* l) {
  __builtin_amdgcn_global_load_lds(
      (__attribute__((address_space(1))) void*)const_cast<void*>(g),
      (__attribute__((address_space(3))) void*)l,
      16, 0, 0);
}

// ---------------------------------------------------------------------------
// K1: fp32 -> bf16 convert (query -> Xbf)
// ---------------------------------------------------------------------------
__global__ __launch_bounds__(256) void k_convert_x(const float* __restrict__ x,
                                                   bf16* __restrict__ o) {
  size_t i = ((size_t)blockIdx.x * 256 + threadIdx.x) * 8;
  floatx4 a = *(const floatx4*)(x + i);
  floatx4 b = *(const floatx4*)(x + i + 4);
  bf16x8 r;
  r[0] = (bf16)a[0]; r[1] = (bf16)a[1]; r[2] = (bf16)a[2]; r[3] = (bf16)a[3];
  r[4] = (bf16)b[0]; r[5] = (bf16)b[1]; r[6] = (bf16)b[2]; r[7] = (bf16)b[3];
  *(bf16x8*)(o + i) = r;
}

// ---------------------------------------------------------------------------
// K2: transpose 4 weight matrices (E x E fp32 (in,out)) -> bf16 (out,in)
// ---------------------------------------------------------------------------
struct TArgs { const float* src[4]; bf16* dst[4]; };

__global__ __launch_bounds__(256) void k_transpose_w(TArgs t) {
  __shared__ float tile[32][33];
  const float* src = t.src[blockIdx.z];
  bf16* dst = t.dst[blockIdx.z];
  int bx = blockIdx.x, by = blockIdx.y;
  int x = threadIdx.x, y = threadIdx.y;  // (32, 8)
#pragma unroll
  for (int i = 0; i < 4; i++) {
    int r = by * 32 + y + i * 8;
    tile[y + i * 8][x] = src[(size_t)r * E_ + bx * 32 + x];
  }
  __syncthreads();
#pragma unroll
  for (int i = 0; i < 4; i++) {
    int r = bx * 32 + y + i * 8;
    dst[(size_t)r * E_ + by * 32 + x] = (bf16)tile[x][y + i * 8];
  }
}

// ---------------------------------------------------------------------------
// K3: QKV MFMA GEMM with TRANSPOSED epilogues.
//  z=0: Q -> QT fp32 [bh][64][2048]   (b128 stores: acc quad = 4 consecutive l)
//  z=1: K -> KT fp32 [bh][64][2048]
//  z=2: V -> VT bf16 [bh][128][2048] rows 0..63 (row 64 = ones via k_vones)
// ---------------------------------------------------------------------------
__global__ __launch_bounds__(256) void k_gemm_qkv(const bf16* __restrict__ A,
                                                  const bf16* __restrict__ Wt,
                                                  const float* __restrict__ bq,
                                                  const float* __restrict__ bk,
                                                  const float* __restrict__ bv,
                                                  float* __restrict__ QT,
                                                  float* __restrict__ KT,
                                                  bf16* __restrict__ VT) {
  __shared__ __attribute__((aligned(16))) bf16 As[128 * 32];
  __shared__ __attribute__((aligned(16))) bf16 Bs[128 * 32];
  const int z = blockIdx.z;
  const bf16* Bt = Wt + (size_t)z * E_ * E_;
  const float* bias = (z == 0) ? bq : (z == 1) ? bk : bv;

  const int tid  = threadIdx.x;
  const int wid  = tid >> 6;
  const int lane = tid & 63;
  const int quad = lane >> 4;
  const int l15  = lane & 15;
  const int wm   = wid >> 1, wn = wid & 1;
  const int bm   = blockIdx.y, bn = blockIdx.x;

  const bf16* ga0 = A  + (size_t)(bm * 128 + wid * 32 + (lane >> 2)) * E_ + (lane & 3) * 8;
  const bf16* ga1 = ga0 + (size_t)16 * E_;
  const bf16* gb0 = Bt + (size_t)(bn * 128 + wid * 32 + (lane >> 2)) * E_ + (lane & 3) * 8;
  const bf16* gb1 = gb0 + (size_t)16 * E_;
  bf16* la = &As[wid * 1024];
  bf16* lb = &Bs[wid * 1024];

  floatx4 acc[4][4] = {};

  for (int kk = 0; kk < E_; kk += 32) {
    async_cp16(ga0, la);        async_cp16(ga1, la + 512);
    async_cp16(gb0, lb);        async_cp16(gb1, lb + 512);
    ga0 += 32; ga1 += 32; gb0 += 32; gb1 += 32;
    __syncthreads();
    bf16x8 af[4], bfm[4];
#pragma unroll
    for (int i = 0; i < 4; i++)
      af[i] = *(const bf16x8*)&As[(wm * 64 + i * 16 + l15) * 32 + quad * 8];
#pragma unroll
    for (int i = 0; i < 4; i++)
      bfm[i] = *(const bf16x8*)&Bs[(wn * 64 + i * 16 + l15) * 32 + quad * 8];
#pragma unroll
    for (int i = 0; i < 4; i++)
#pragma unroll
      for (int j = 0; j < 4; j++)
        acc[i][j] = __builtin_amdgcn_mfma_f32_16x16x32_bf16(af[i], bfm[j], acc[i][j], 0, 0, 0);
    __syncthreads();
  }

  // transposed epilogue: col c -> (h, d); rows r0..r0+3 -> (b, l..l+3)
#pragma unroll
  for (int i = 0; i < 4; i++)
#pragma unroll
    for (int j = 0; j < 4; j++) {
      const int c  = bn * 128 + wn * 64 + j * 16 + l15;
      const int r0 = bm * 128 + wm * 64 + i * 16 + quad * 4;
      const int h = c >> 6, d = c & 63;
      const int b = r0 >> 11, l = r0 & 2047;
      const float bv_ = bias[c];
      floatx4 v = acc[i][j];
      v[0] += bv_; v[1] += bv_; v[2] += bv_; v[3] += bv_;
      if (z == 0) {
        *(floatx4*)&QT[(((size_t)(b * 16 + h) * 64 + d) * 2048) + l] = v;
      } else if (z == 1) {
        *(floatx4*)&KT[(((size_t)(b * 16 + h) * 64 + d) * 2048) + l] = v;
      } else {
        bf16x4 r; r[0] = (bf16)v[0]; r[1] = (bf16)v[1]; r[2] = (bf16)v[2]; r[3] = (bf16)v[3];
        *(bf16x4*)&VT[(((size_t)(b * 16 + h) * 128 + d) * 2048) + l] = r;
      }
    }
}

// ---------------------------------------------------------------------------
// K4: write ones row VT[bh][64][:]
// ---------------------------------------------------------------------------
__global__ __launch_bounds__(256) void k_vones(bf16* __restrict__ VT) {
  const int bh = blockIdx.x;
  bf16x8 one;
#pragma unroll
  for (int i = 0; i < 8; i++) one[i] = (bf16)1.0f;
  *(bf16x8*)&VT[((size_t)(bh * 128 + 64) * 2048) + threadIdx.x * 8] = one;
}

// ---------------------------------------------------------------------------
// K5: k-features: KT (fp32, [bh][64][l]) -> FkT (bf16, [bh][128][l])
//  rows 0..63 = softmax(k)*sin_l, 64..127 = softmax(k)*cos_l.
//  Thread = one l; column reads/writes are lane-coalesced.
// ---------------------------------------------------------------------------
__global__ __launch_bounds__(256) void k_kfeat(const float* __restrict__ KT,
                                               bf16* __restrict__ FkT) {
  const int bh = blockIdx.y;
  const int l  = blockIdx.x * 256 + threadIdx.x;
  const float* kp = KT + ((size_t)bh * 64) * 2048 + l;
  float xv[64];
#pragma unroll
  for (int d = 0; d < 64; d++) xv[d] = kp[(size_t)d * 2048];
  float mx = -1e30f;
#pragma unroll
  for (int d = 0; d < 64; d++) mx = fmaxf(mx, xv[d]);
  float s = 0.f;
#pragma unroll
  for (int d = 0; d < 64; d++) { xv[d] = __expf(xv[d] - mx); s += xv[d]; }
  const float inv = 1.f / s;
  const float ang = PI2_ * (float)(l + 1) / (float)L_;
  const float sn = __sinf(ang), cs = __cosf(ang);
  bf16* fp = FkT + ((size_t)bh * 128) * 2048 + l;
#pragma unroll
  for (int d = 0; d < 64; d++) {
    const float p = xv[d] * inv;
    fp[(size_t)d * 2048]        = (bf16)(p * sn);
    fp[(size_t)(64 + d) * 2048] = (bf16)(p * cs);
  }
}

// ---------------------------------------------------------------------------
// K6: KV GEMM (MFMA): per (kseg, bh): C[f<128][d'<128] = FkT(128 x 1024seg) . VT^T
//  kvp fp32 [kseg][bh][128][128]. col 64 = ks (ones row); cols 65..127 junk.
// ---------------------------------------------------------------------------
__global__ __launch_bounds__(256) void k_gemm_kv(const bf16* __restrict__ FkT,
                                                 const bf16* __restrict__ VT,
                                                 float* __restrict__ kvp) {
  __shared__ __attribute__((aligned(16))) bf16 As[128 * 32];
  __shared__ __attribute__((aligned(16))) bf16 Bs[128 * 32];
  const int kseg = blockIdx.x;   // 0..1
  const int bh   = blockIdx.y;   // 0..127

  const int tid  = threadIdx.x;
  const int wid  = tid >> 6;
  const int lane = tid & 63;
  const int quad = lane >> 4;
  const int l15  = lane & 15;
  const int wm   = wid >> 1, wn = wid & 1;

  const bf16* Ab = FkT + (size_t)bh * 128 * 2048 + kseg * 1024;
  const bf16* Bb = VT  + (size_t)bh * 128 * 2048 + kseg * 1024;
  const bf16* ga0 = Ab + (size_t)(wid * 32 + (lane >> 2)) * 2048 + (lane & 3) * 8;
  const bf16* ga1 = ga0 + (size_t)16 * 2048;
  const bf16* gb0 = Bb + (size_t)(wid * 32 + (lane >> 2)) * 2048 + (lane & 3) * 8;
  const bf16* gb1 = gb0 + (size_t)16 * 2048;
  bf16* la = &As[wid * 1024];
  bf16* lb = &Bs[wid * 1024];

  floatx4 acc[4][4] = {};

  for (int kk = 0; kk < 1024; kk += 32) {
    async_cp16(ga0, la);        async_cp16(ga1, la + 512);
    async_cp16(gb0, lb);        async_cp16(gb1, lb + 512);
    ga0 += 32; ga1 += 32; gb0 += 32; gb1 += 32;
    __syncthreads();
    bf16x8 af[4], bfm[4];
#pragma unroll
    for (int i = 0; i < 4; i++)
      af[i] = *(const bf16x8*)&As[(wm * 64 + i * 16 + l15) * 32 + quad * 8];
#pragma unroll
    for (int i = 0; i < 4; i++)
      bfm[i] = *(const bf16x8*)&Bs[(wn * 64 + i * 16 + l15) * 32 + quad * 8];
#pragma unroll
    for (int i = 0; i < 4; i++)
#pragma unroll
      for (int j = 0; j < 4; j++)
        acc[i][j] = __builtin_amdgcn_mfma_f32_16x16x32_bf16(af[i], bfm[j], acc[i][j], 0, 0, 0);
    __syncthreads();
  }

  float* C = kvp + ((size_t)(kseg * 128 + bh)) * 128 * 128;
#pragma unroll
  for (int i = 0; i < 4; i++)
#pragma unroll
    for (int j = 0; j < 4; j++) {
      const int col = wn * 64 + j * 16 + l15;
#pragma unroll
      for (int r = 0; r < 4; r++) {
        const int row = wm * 64 + i * 16 + quad * 4 + r;
        C[(size_t)row * 128 + col] = acc[i][j][r];
      }
    }
}

// ---------------------------------------------------------------------------
// K7: SV/CV: svcv[bh][r][0] = sum_l sin_l * VT[bh][r][l], [1] = cos version.
//  r in [0,65): r=64 is the ones row -> gives Ssn, Scs.
// ---------------------------------------------------------------------------
__global__ __launch_bounds__(256) void k_svcv(const bf16* __restrict__ VT,
                                              float* __restrict__ svcv) {
  __shared__ float sns[2048];
  __shared__ float css[2048];
  const int bh = blockIdx.x;
  const int t = threadIdx.x;
  const int wid = t >> 6, lane = t & 63;
#pragma unroll
  for (int i = 0; i < 8; i++) {
    const int l = t + i * 256;
    const float ang = PI2_ * (float)(l + 1) / (float)L_;
    sns[l] = __sinf(ang);
    css[l] = __cosf(ang);
  }
  __syncthreads();
  for (int r = wid; r < 65; r += 4) {
    const bf16* vp = VT + ((size_t)(bh * 128 + r)) * 2048;
    float as = 0.f, ac = 0.f;
#pragma unroll
    for (int pass = 0; pass < 4; pass++) {
      const int el = pass * 512 + lane * 8;
      bf16x8 v = *(const bf16x8*)(vp + el);
#pragma unroll
      for (int j = 0; j < 8; j++) {
        const float vf = (float)v[j];
        as += sns[el + j] * vf;
        ac += css[el + j] * vf;
      }
    }
#pragma unroll
    for (int o = 1; o < 64; o <<= 1) { as += __shfl_xor(as, o); ac += __shfl_xor(ac, o); }
    if (lane == 0) {
      svcv[((size_t)bh * 65 + r) * 2]     = as;
      svcv[((size_t)bh * 65 + r) * 2 + 1] = ac;
    }
  }
}

// ---------------------------------------------------------------------------
// K8: consts: reduce kv partials -> KVT bf16 [bh][64][160] + ksbuf [bh][136].
//  KVT[d'][f]: f<128 = KV[f][d'], f=128 = U=63*SV-SK0, f=129 = W, f>=130 = 0.
//  ksbuf: [0..63]=ks0, [64..127]=ks1, [128]=SKS0, [129]=SKS1, [130]=Ssn, [131]=Scs
// ---------------------------------------------------------------------------
__global__ __launch_bounds__(256) void k_consts(const float* __restrict__ kvp,
                                                const float* __restrict__ svcv,
                                                bf16* __restrict__ KVT,
                                                float* __restrict__ ksbuf) {
  const int bh = blockIdx.x;
  const int t = threadIdx.x;
  const float* P0 = kvp + ((size_t)bh) * 128 * 128;
  const float* P1 = kvp + ((size_t)(128 + bh)) * 128 * 128;
  if (t < 64) {
    const int dp = t;
    bf16* kr = KVT + ((size_t)(bh * 64 + dp)) * 160;
    float sk0 = 0.f, sk1 = 0.f;
#pragma unroll 8
    for (int f = 0; f < 128; f++) {
      const float v = P0[(size_t)f * 128 + dp] + P1[(size_t)f * 128 + dp];
      kr[f] = (bf16)v;
      if (f < 64) sk0 += v; else sk1 += v;
    }
    // ks0/ks1 from ones column (d'=64)
    const float ks0 = P0[(size_t)dp * 128 + 64] + P1[(size_t)dp * 128 + 64];
    const float ks1 = P0[(size_t)(64 + dp) * 128 + 64] + P1[(size_t)(64 + dp) * 128 + 64];
    ksbuf[(size_t)bh * 136 + dp]      = ks0;
    ksbuf[(size_t)bh * 136 + 64 + dp] = ks1;
    float sks0 = ks0, sks1 = ks1;
#pragma unroll
    for (int o = 1; o < 64; o <<= 1) { sks0 += __shfl_xor(sks0, o); sks1 += __shfl_xor(sks1, o); }
    const float SV = svcv[((size_t)bh * 65 + dp) * 2];
    const float CV = svcv[((size_t)bh * 65 + dp) * 2 + 1];
    kr[128] = (bf16)(63.f * SV - sk0);
    kr[129] = (bf16)(63.f * CV - sk1);
#pragma unroll
    for (int f = 130; f < 160; f++) kr[f] = (bf16)0.f;
    if (dp == 0) {
      ksbuf[(size_t)bh * 136 + 128] = sks0;
      ksbuf[(size_t)bh * 136 + 129] = sks1;
      ksbuf[(size_t)bh * 136 + 130] = svcv[((size_t)bh * 65 + 64) * 2];      // Ssn
      ksbuf[(size_t)bh * 136 + 131] = svcv[((size_t)bh * 65 + 64) * 2 + 1];  // Scs
    }
  }
}

// ---------------------------------------------------------------------------
// K9: fused attention: q-softmax + z1/z2 -> Aq rows in LDS -> MFMA vs KVT
//  block = (lc: 128 l-rows, bh). out attnb[(l*B+b)][h*64+d'] bf16.
//  LDS: Abuf [128][168] bf16 (42KB) + Bbuf [64][168] bf16 (21KB) + ks 544B.
// ---------------------------------------------------------------------------
#define ASTR 168
__global__ __launch_bounds__(256) void k_attn(const float* __restrict__ QT,
                                              const bf16* __restrict__ KVT,
                                              const float* __restrict__ ksbuf,
                                              bf16* __restrict__ attn) {
  __shared__ __attribute__((aligned(16))) bf16 Abuf[128 * ASTR];
  __shared__ __attribute__((aligned(16))) bf16 Bbuf[64 * ASTR];
  __shared__ float ksl[136];
  const int lc = blockIdx.x;   // 0..15
  const int bh = blockIdx.y;
  const int b = bh >> 4, h = bh & 15;
  const int t = threadIdx.x;

  // phase 0: KVT row-block + ks scalars -> LDS
  {
    const bf16* src = KVT + (size_t)bh * 64 * 160;
#pragma unroll
    for (int i = 0; i < 5; i++) {
      const int idx = t + i * 256;           // 1280 chunks of 8 bf16
      const int row = idx / 20, ch = idx % 20;
      *(bf16x8*)&Bbuf[row * ASTR + ch * 8] = *(const bf16x8*)(src + row * 160 + ch * 8);
    }
    if (t < 132) ksl[t] = ksbuf[(size_t)bh * 136 + t];
  }
  __syncthreads();

  // phase 1: threads t<128 compute Aq row for l = lc*128 + t
  if (t < 128) {
    const int l = lc * 128 + t;
    const float* qp = QT + ((size_t)bh * 64) * 2048 + l;
    float xv[64];
#pragma unroll
    for (int d = 0; d < 64; d++) xv[d] = qp[(size_t)d * 2048];
    float mx = -1e30f;
#pragma unroll
    for (int d = 0; d < 64; d++) mx = fmaxf(mx, xv[d]);
    float s = 0.f;
#pragma unroll
    for (int d = 0; d < 64; d++) { xv[d] = __expf(xv[d] - mx); s += xv[d]; }
    const float inv = 1.f / s;
    float t0 = 0.f, t1 = 0.f;
#pragma unroll
    for (int d = 0; d < 64; d++) {
      xv[d] *= inv;                       // p
      t0 += xv[d] * ksl[d];
      t1 += xv[d] * ksl[64 + d];
    }
    const float SKS0 = ksl[128], SKS1 = ksl[129], Ssn = ksl[130], Scs = ksl[131];
    const float ang = PI2_ * (float)(l + 1) / (float)L_;
    const float sn = __sinf(ang), cs = __cosf(ang);
    const float den1 = sn * t0 + cs * t1;
    const float den2 = sn * (63.f * Ssn - SKS0 + t0) + cs * (63.f * Scs - SKS1 + t1);
    const float z1 = 1.f / fmaxf(den1, EPS_);
    const float z2 = 1.f / fmaxf(den2, EPS_);
    const float zz = z1 + z2;
    const float a0 = zz * sn, a1 = zz * cs;
    bf16* ar = &Abuf[t * ASTR];
#pragma unroll
    for (int g = 0; g < 8; g++) {
      bf16x8 w;
#pragma unroll
      for (int j = 0; j < 8; j++) w[j] = (bf16)(a0 * xv[g * 8 + j]);
      *(bf16x8*)(ar + g * 8) = w;
    }
#pragma unroll
    for (int g = 0; g < 8; g++) {
      bf16x8 w;
#pragma unroll
      for (int j = 0; j < 8; j++) w[j] = (bf16)(a1 * xv[g * 8 + j]);
      *(bf16x8*)(ar + 64 + g * 8) = w;
    }
    bf16x8 wt = {};
    wt[0] = (bf16)(z2 * sn); wt[1] = (bf16)(z2 * cs);
    *(bf16x8*)(ar + 128) = wt;
    bf16x8 zr = {};
    *(bf16x8*)(ar + 136) = zr;
    *(bf16x8*)(ar + 144) = zr;
    *(bf16x8*)(ar + 152) = zr;
  }
  __syncthreads();

  // phase 2: MFMA: M=128 (l), N=64 (d'), K=160
  const int wid = t >> 6, lane = t & 63;
  const int quad = lane >> 4, l15 = lane & 15;
  const int wm = wid >> 1, wn = wid & 1;
  floatx4 acc[4][2] = {};
#pragma unroll
  for (int kk = 0; kk < 5; kk++) {
    bf16x8 af[4], bfm[2];
#pragma unroll
    for (int i = 0; i < 4; i++)
      af[i] = *(const bf16x8*)&Abuf[(wm * 64 + i * 16 + l15) * ASTR + kk * 32 + quad * 8];
#pragma unroll
    for (int j = 0; j < 2; j++)
      bfm[j] = *(const bf16x8*)&Bbuf[(wn * 32 + j * 16 + l15) * ASTR + kk * 32 + quad * 8];
#pragma unroll
    for (int i = 0; i < 4; i++)
#pragma unroll
      for (int j = 0; j < 2; j++)
        acc[i][j] = __builtin_amdgcn_mfma_f32_16x16x32_bf16(af[i], bfm[j], acc[i][j], 0, 0, 0);
  }
#pragma unroll
  for (int i = 0; i < 4; i++)
#pragma unroll
    for (int j = 0; j < 2; j++) {
      const int dp = wn * 32 + j * 16 + l15;
#pragma unroll
      for (int r = 0; r < 4; r++) {
        const int l = lc * 128 + wm * 64 + i * 16 + quad * 4 + r;
        attn[((size_t)l * B_ + b) * E_ + h * 64 + dp] = (bf16)acc[i][j][r];
      }
    }
}

// ---------------------------------------------------------------------------
// K10: final projection GEMM: d_out = attnb @ WoT^T + bo (fp32 out)
// ---------------------------------------------------------------------------
__global__ __launch_bounds__(256) void k_gemm_final(const bf16* __restrict__ A,
                                                    const bf16* __restrict__ Bt,
                                                    const float* __restrict__ bias,
                                                    float* __restrict__ C) {
  __shared__ __attribute__((aligned(16))) bf16 As[128 * 32];
  __shared__ __attribute__((aligned(16))) bf16 Bs[128 * 32];
  const int tid  = threadIdx.x;
  const int wid  = tid >> 6;
  const int lane = tid & 63;
  const int quad = lane >> 4;
  const int l15  = lane & 15;
  const int wm   = wid >> 1, wn = wid & 1;
  const int bm   = blockIdx.y, bn = blockIdx.x;

  const bf16* ga0 = A  + (size_t)(bm * 128 + wid * 32 + (lane >> 2)) * E_ + (lane & 3) * 8;
  const bf16* ga1 = ga0 + (size_t)16 * E_;
  const bf16* gb0 = Bt + (size_t)(bn * 128 + wid * 32 + (lane >> 2)) * E_ + (lane & 3) * 8;
  const bf16* gb1 = gb0 + (size_t)16 * E_;
  bf16* la = &As[wid * 1024];
  bf16* lb = &Bs[wid * 1024];

  floatx4 acc[4][4] = {};
  for (int kk = 0; kk < E_; kk += 32) {
    async_cp16(ga0, la);        async_cp16(ga1, la + 512);
    async_cp16(gb0, lb);        async_cp16(gb1, lb + 512);
    ga0 += 32; ga1 += 32; gb0 += 32; gb1 += 32;
    __syncthreads();
    bf16x8 af[4], bfm[4];
#pragma unroll
    for (int i = 0; i < 4; i++)
      af[i] = *(const bf16x8*)&As[(wm * 64 + i * 16 + l15) * 32 + quad * 8];
#pragma unroll
    for (int i = 0; i < 4; i++)
      bfm[i] = *(const bf16x8*)&Bs[(wn * 64 + i * 16 + l15) * 32 + quad * 8];
#pragma unroll
    for (int i = 0; i < 4; i++)
#pragma unroll
      for (int j = 0; j < 4; j++)
        acc[i][j] = __builtin_amdgcn_mfma_f32_16x16x32_bf16(af[i], bfm[j], acc[i][j], 0, 0, 0);
    __syncthreads();
  }
#pragma unroll
  for (int i = 0; i < 4; i++)
#pragma unroll
    for (int j = 0; j < 4; j++) {
      const int col = bn * 128 + wn * 64 + j * 16 + l15;
      const float bv = bias[col];
#pragma unroll
      for (int r = 0; r < 4; r++) {
        const int row = bm * 128 + wm * 64 + i * 16 + quad * 4 + r;
        C[(size_t)row * E_ + col] = acc[i][j][r] + bv;
      }
    }
}

// ---------------------------------------------------------------------------
// Workspace layout (bytes), max 243,269,632:
//  QT   fp32 [128][64][2048]   @ 0            (67,108,864)
//  KT   fp32 [128][64][2048]   @ 67,108,864   (67,108,864)  dead after kfeat
//    kvp  fp32 [2][128][128][128] @ 67,108,864 (16,777,216)  overlays KT
//    KVT  bf16 [128][64][160]     @ 83,886,080 ( 2,621,440)
//    ksbuf fp32 [128][136]        @ 86,507,520 (    69,632)
//    svcv fp32 [128][65][2]       @ 86,577,152 (    66,560)
//  VT   bf16 [128][128][2048]  @ 134,217,728  (67,108,864)
//  Wt   bf16 x4                @ 201,326,592  ( 8,388,608)
//  Xbf  bf16                   @ 209,715,200  (33,554,432)  dead after QKV
//    attnb bf16                 @ 209,715,200  overlays Xbf
//  FkT  bf16 [128][128][2048]  -> d_out scratch (exactly 67,108,864)
// ---------------------------------------------------------------------------
extern "C" void kernel_launch(void* const* d_in, const int* in_sizes, int n_in,
                              void* d_out, int out_size, void* d_ws, size_t ws_size,
                              hipStream_t stream) {
  (void)in_sizes; (void)n_in; (void)out_size; (void)ws_size;
  const float* query = (const float*)d_in[0];
  const float* Wq = (const float*)d_in[1];
  const float* bq = (const float*)d_in[2];
  const float* Wk = (const float*)d_in[3];
  const float* bk = (const float*)d_in[4];
  const float* Wv = (const float*)d_in[5];
  const float* bv = (const float*)d_in[6];
  const float* Wo = (const float*)d_in[7];
  const float* bo = (const float*)d_in[8];

  char* ws = (char*)d_ws;
  float* QT   = (float*)(ws + 0);
  float* KT   = (float*)(ws + 67108864);
  float* kvp  = (float*)(ws + 67108864);
  bf16*  KVT  = (bf16*) (ws + 83886080);
  float* ksbuf= (float*)(ws + 86507520);
  float* svcv = (float*)(ws + 86577152);
  bf16*  VT   = (bf16*) (ws + 134217728);
  bf16*  Wt   = (bf16*) (ws + 201326592);
  bf16*  Xbf  = (bf16*) (ws + 209715200);
  bf16*  attnb= (bf16*) (ws + 209715200);
  bf16*  FkT  = (bf16*) d_out;

  // 1) X -> bf16
  k_convert_x<<<(M_ * E_) / (256 * 8), 256, 0, stream>>>(query, Xbf);

  // 2) W^T -> bf16 for all four weights
  TArgs ta;
  ta.src[0] = Wq; ta.src[1] = Wk; ta.src[2] = Wv; ta.src[3] = Wo;
  ta.dst[0] = Wt;                       ta.dst[1] = Wt + (size_t)E_ * E_;
  ta.dst[2] = Wt + (size_t)2 * E_ * E_; ta.dst[3] = Wt + (size_t)3 * E_ * E_;
  k_transpose_w<<<dim3(32, 32, 4), dim3(32, 8), 0, stream>>>(ta);

  // 3) QKV GEMM with transposed epilogues
  k_gemm_qkv<<<dim3(E_ / 128, M_ / 128, 3), 256, 0, stream>>>(Xbf, Wt, bq, bk, bv, QT, KT, VT);

  // 4) ones row for VT
  k_vones<<<128, 256, 0, stream>>>(VT);

  // 5) k-features (KT -> FkT in d_out scratch)
  k_kfeat<<<dim3(8, 128), 256, 0, stream>>>(KT, FkT);

  // 6) KV GEMM (2 k-segments)
  k_gemm_kv<<<dim3(2, 128), 256, 0, stream>>>(FkT, VT, kvp);

  // 7) SV/CV/Ssn/Scs
  k_svcv<<<128, 256, 0, stream>>>(VT, svcv);

  // 8) consts: KVT + ksbuf
  k_consts<<<128, 256, 0, stream>>>(kvp, svcv, KVT, ksbuf);

  // 9) fused attention
  k_attn<<<dim3(16, 128), 256, 0, stream>>>(QT, KVT, ksbuf, attnb);

  // 10) final projection -> d_out
  k_gemm_final<<<dim3(E_ / 128, M_ / 128), 256, 0, stream>>>(attnb, Wt + (size_t)3 * E_ * E_, bo, (float*)d_out);
}

// Round 4
// 394.669 us; speedup vs baseline: 2.2637x; 1.1894x over previous
//
#include <hip/hip_runtime.h>
#include <hip/hip_bf16.h>
#include <cstdint>

// Problem constants
#define B_   8
#define L_   2048
#define E_   1024
#define H_   16
#define D_   64
#define M_   (B_ * L_)
#define EPS_ 1e-6f
#define PI2_ 1.57079632679f

typedef __bf16 bf16;
typedef __bf16 bf16x8 __attribute__((ext_vector_type(8)));
typedef __bf16 bf16x4 __attribute__((ext_vector_type(4)));
typedef float  floatx4 __attribute__((ext_vector_type(4)));

__device__ inline void async_cp16(const void* g, void* l) {
  __builtin_amdgcn_global_load_lds(
      (__attribute__((address_space(1))) void*)const_cast<void*>(g),
      (__attribute__((address_space(3))) void*)l,
      16, 0, 0);
}

// ---------------------------------------------------------------------------
// K1: fp32 -> bf16 convert (query -> Xbf)
// ---------------------------------------------------------------------------
__global__ __launch_bounds__(256) void k_convert_x(const float* __restrict__ x,
                                                   bf16* __restrict__ o) {
  size_t i = ((size_t)blockIdx.x * 256 + threadIdx.x) * 8;
  floatx4 a = *(const floatx4*)(x + i);
  floatx4 b = *(const floatx4*)(x + i + 4);
  bf16x8 r;
  r[0] = (bf16)a[0]; r[1] = (bf16)a[1]; r[2] = (bf16)a[2]; r[3] = (bf16)a[3];
  r[4] = (bf16)b[0]; r[5] = (bf16)b[1]; r[6] = (bf16)b[2]; r[7] = (bf16)b[3];
  *(bf16x8*)(o + i) = r;
}

// ---------------------------------------------------------------------------
// K2: transpose 4 weight matrices (E x E fp32 (in,out)) -> bf16 (out,in)
// ---------------------------------------------------------------------------
struct TArgs { const float* src[4]; bf16* dst[4]; };

__global__ __launch_bounds__(256) void k_transpose_w(TArgs t) {
  __shared__ float tile[32][33];
  const float* src = t.src[blockIdx.z];
  bf16* dst = t.dst[blockIdx.z];
  int bx = blockIdx.x, by = blockIdx.y;
  int x = threadIdx.x, y = threadIdx.y;  // (32, 8)
#pragma unroll
  for (int i = 0; i < 4; i++) {
    int r = by * 32 + y + i * 8;
    tile[y + i * 8][x] = src[(size_t)r * E_ + bx * 32 + x];
  }
  __syncthreads();
#pragma unroll
  for (int i = 0; i < 4; i++) {
    int r = bx * 32 + y + i * 8;
    dst[(size_t)r * E_ + by * 32 + x] = (bf16)tile[x][y + i * 8];
  }
}

// ---------------------------------------------------------------------------
// K3: QKV MFMA GEMM, 1D grid with XCD swizzle:
//   bn = id&7 (XCD-affine: each XCD keeps its 3 W-tiles L2-resident),
//   z innermost per bm (A-tile L2-hot across q/k/v on the same XCD).
//  Transposed epilogues: QT/KT fp32 [bh][64][2048], VT bf16 [bh][64][2048].
// ---------------------------------------------------------------------------
__global__ __launch_bounds__(256) void k_gemm_qkv(const bf16* __restrict__ A,
                                                  const bf16* __restrict__ Wt,
                                                  const float* __restrict__ bq,
                                                  const float* __restrict__ bk,
                                                  const float* __restrict__ bv,
                                                  float* __restrict__ QT,
                                                  float* __restrict__ KT,
                                                  bf16* __restrict__ VT) {
  __shared__ __attribute__((aligned(16))) bf16 As[128 * 32];
  __shared__ __attribute__((aligned(16))) bf16 Bs[128 * 32];
  const int id = blockIdx.x;
  const int bn = id & 7;
  const int q  = id >> 3;
  const int bm = q / 3;
  const int z  = q - bm * 3;
  const bf16* Bt = Wt + (size_t)z * E_ * E_;
  const float* bias = (z == 0) ? bq : (z == 1) ? bk : bv;

  const int tid  = threadIdx.x;
  const int wid  = tid >> 6;
  const int lane = tid & 63;
  const int quad = lane >> 4;
  const int l15  = lane & 15;
  const int wm   = wid >> 1, wn = wid & 1;

  const bf16* ga0 = A  + (size_t)(bm * 128 + wid * 32 + (lane >> 2)) * E_ + (lane & 3) * 8;
  const bf16* ga1 = ga0 + (size_t)16 * E_;
  const bf16* gb0 = Bt + (size_t)(bn * 128 + wid * 32 + (lane >> 2)) * E_ + (lane & 3) * 8;
  const bf16* gb1 = gb0 + (size_t)16 * E_;
  bf16* la = &As[wid * 1024];
  bf16* lb = &Bs[wid * 1024];

  floatx4 acc[4][4] = {};

  for (int kk = 0; kk < E_; kk += 32) {
    async_cp16(ga0, la);        async_cp16(ga1, la + 512);
    async_cp16(gb0, lb);        async_cp16(gb1, lb + 512);
    ga0 += 32; ga1 += 32; gb0 += 32; gb1 += 32;
    __syncthreads();
    bf16x8 af[4], bfm[4];
#pragma unroll
    for (int i = 0; i < 4; i++)
      af[i] = *(const bf16x8*)&As[(wm * 64 + i * 16 + l15) * 32 + quad * 8];
#pragma unroll
    for (int i = 0; i < 4; i++)
      bfm[i] = *(const bf16x8*)&Bs[(wn * 64 + i * 16 + l15) * 32 + quad * 8];
#pragma unroll
    for (int i = 0; i < 4; i++)
#pragma unroll
      for (int j = 0; j < 4; j++)
        acc[i][j] = __builtin_amdgcn_mfma_f32_16x16x32_bf16(af[i], bfm[j], acc[i][j], 0, 0, 0);
    __syncthreads();
  }

  // transposed epilogue: col c -> (h, d); rows r0..r0+3 -> (b, l..l+3)
#pragma unroll
  for (int i = 0; i < 4; i++)
#pragma unroll
    for (int j = 0; j < 4; j++) {
      const int c  = bn * 128 + wn * 64 + j * 16 + l15;
      const int r0 = bm * 128 + wm * 64 + i * 16 + quad * 4;
      const int h = c >> 6, d = c & 63;
      const int b = r0 >> 11, l = r0 & 2047;
      const float bv_ = bias[c];
      floatx4 v = acc[i][j];
      v[0] += bv_; v[1] += bv_; v[2] += bv_; v[3] += bv_;
      if (z == 0) {
        *(floatx4*)&QT[(((size_t)(b * 16 + h) * 64 + d) * 2048) + l] = v;
      } else if (z == 1) {
        *(floatx4*)&KT[(((size_t)(b * 16 + h) * 64 + d) * 2048) + l] = v;
      } else {
        bf16x4 r; r[0] = (bf16)v[0]; r[1] = (bf16)v[1]; r[2] = (bf16)v[2]; r[3] = (bf16)v[3];
        *(bf16x4*)&VT[(((size_t)(b * 16 + h) * 64 + d) * 2048) + l] = r;
      }
    }
}

// ---------------------------------------------------------------------------
// K4: fused k-softmax + features + KV GEMM (kfeat folded into the K-loop).
//  Grid (kseg=4, bh=128). Per iter (BK=32 l's):
//   - stage KT[64][32] fp32 + VT[64][32] bf16 via global_load_lds
//   - per-column softmax over d (8 threads/column, d = ii+8j stride-8 rows)
//   - features -> Abuf[128][40] bf16 (rows: f<64 = p*sn, f>=64 = p*cs)
//   - MFMA M=128(f) x N=64(d') x K=32 + A-rowsum (= ks partials)
//  Out: kvp fp32 [kseg][bh][f=128][68]: cols 0..63 = KV, col 64 = rowsum.
// ---------------------------------------------------------------------------
#define AST 40
__global__ __launch_bounds__(256) void k_kv(const float* __restrict__ KT,
                                            const bf16* __restrict__ VT,
                                            float* __restrict__ kvp) {
  __shared__ __attribute__((aligned(16))) float kt[64 * 32];    // 8 KB
  __shared__ __attribute__((aligned(16))) bf16  vt[64 * 32];    // 4 KB
  __shared__ __attribute__((aligned(16))) bf16  Abuf[128 * AST];// 10 KB
  const int kseg = blockIdx.x;
  const int bh   = blockIdx.y;
  const int t = threadIdx.x;
  const int wid = t >> 6, lane = t & 63;
  const int quad = lane >> 4, l15 = lane & 15;
  const int wm = wid >> 1, wn = wid & 1;
  const int c = t >> 3, ii = t & 7;      // softmax: column c (l), sub ii

  const float* ktg = KT + (size_t)bh * 64 * 2048;
  const bf16*  vtg = VT + (size_t)bh * 64 * 2048;

  floatx4 acc[4][2] = {};
  float rs = 0.f;

  for (int it = 0; it < 16; it++) {
    const int l0 = kseg * 512 + it * 32;
    // stage KT: wave wid covers rows wid*16..+15 (2 insts of 8 rows)
    {
      const int r = lane >> 3, ch = lane & 7;
      const float* g0 = ktg + (size_t)(wid * 16 + r) * 2048 + l0 + ch * 4;
      const float* g1 = ktg + (size_t)(wid * 16 + 8 + r) * 2048 + l0 + ch * 4;
      async_cp16(g0, &kt[(wid * 16) * 32]);
      async_cp16(g1, &kt[(wid * 16 + 8) * 32]);
    }
    // stage VT: wave wid covers rows wid*16..+15 (1 inst)
    {
      const int r = lane >> 2, ch = lane & 3;
      const bf16* g0 = vtg + (size_t)(wid * 16 + r) * 2048 + l0 + ch * 8;
      async_cp16(g0, &vt[(wid * 16) * 32]);
    }
    __syncthreads();

    // per-column softmax, this thread owns d = ii + 8j
    float xv[8];
#pragma unroll
    for (int j = 0; j < 8; j++) xv[j] = kt[(ii + 8 * j) * 32 + c];
    float mx = xv[0];
#pragma unroll
    for (int j = 1; j < 8; j++) mx = fmaxf(mx, xv[j]);
    mx = fmaxf(mx, __shfl_xor(mx, 1));
    mx = fmaxf(mx, __shfl_xor(mx, 2));
    mx = fmaxf(mx, __shfl_xor(mx, 4));
    float s = 0.f;
#pragma unroll
    for (int j = 0; j < 8; j++) { xv[j] = __expf(xv[j] - mx); s += xv[j]; }
    s += __shfl_xor(s, 1); s += __shfl_xor(s, 2); s += __shfl_xor(s, 4);
    const float inv = 1.f / s;
    const int l = l0 + c;
    const float ang = PI2_ * (float)(l + 1) / (float)L_;
    const float sn = __sinf(ang), cs = __cosf(ang);
#pragma unroll
    for (int j = 0; j < 8; j++) {
      const float p = xv[j] * inv;
      const int f = ii + 8 * j;
      Abuf[f * AST + c]        = (bf16)(p * sn);
      Abuf[(64 + f) * AST + c] = (bf16)(p * cs);
    }
    __syncthreads();

    // A-rowsums (ks partials): thread f<128 sums its Abuf row
    if (t < 128) {
      float r8 = 0.f;
#pragma unroll
      for (int g = 0; g < 4; g++) {
        bf16x8 v = *(const bf16x8*)&Abuf[t * AST + g * 8];
#pragma unroll
        for (int e = 0; e < 8; e++) r8 += (float)v[e];
      }
      rs += r8;
    }

    // MFMA
    bf16x8 af[4], bfm[2];
#pragma unroll
    for (int i = 0; i < 4; i++)
      af[i] = *(const bf16x8*)&Abuf[(wm * 64 + i * 16 + l15) * AST + quad * 8];
#pragma unroll
    for (int j = 0; j < 2; j++)
      bfm[j] = *(const bf16x8*)&vt[(wn * 32 + j * 16 + l15) * 32 + quad * 8];
#pragma unroll
    for (int i = 0; i < 4; i++)
#pragma unroll
      for (int j = 0; j < 2; j++)
        acc[i][j] = __builtin_amdgcn_mfma_f32_16x16x32_bf16(af[i], bfm[j], acc[i][j], 0, 0, 0);
    __syncthreads();
  }

  float* C = kvp + (size_t)(kseg * 128 + bh) * 128 * 68;
#pragma unroll
  for (int i = 0; i < 4; i++)
#pragma unroll
    for (int j = 0; j < 2; j++) {
      const int col = wn * 32 + j * 16 + l15;
#pragma unroll
      for (int r = 0; r < 4; r++) {
        const int row = wm * 64 + i * 16 + quad * 4 + r;
        C[(size_t)row * 68 + col] = acc[i][j][r];
      }
    }
  if (t < 128) C[(size_t)t * 68 + 64] = rs;
}

// ---------------------------------------------------------------------------
// K5: consts: reduce 4 kvp partials -> KVT bf16 [bh][64][160] + ksbuf.
//  Identities: SV = sk0, CV = sk1, Ssn = SKS0, Scs = SKS1 (since sum_d p = 1)
//   -> KVT[.][128] = 62*sk0, [129] = 62*sk1; den2 uses 62*SKS0/62*SKS1.
//  ksbuf[bh][136]: [0..63]=ks0, [64..127]=ks1, [128]=SKS0, [129]=SKS1.
// ---------------------------------------------------------------------------
__global__ __launch_bounds__(64) void k_consts(const float* __restrict__ kvp,
                                               bf16* __restrict__ KVT,
                                               float* __restrict__ ksbuf) {
  const int bh = blockIdx.x;
  const int dp = threadIdx.x;  // 0..63
  const size_t gs = (size_t)128 * 128 * 68;
  const float* P = kvp + (size_t)bh * 128 * 68;
  bf16* kr = KVT + (size_t)(bh * 64 + dp) * 160;
  float sk0 = 0.f, sk1 = 0.f;
#pragma unroll 8
  for (int f = 0; f < 128; f++) {
    float v = P[(size_t)f * 68 + dp] + P[gs + (size_t)f * 68 + dp]
            + P[2 * gs + (size_t)f * 68 + dp] + P[3 * gs + (size_t)f * 68 + dp];
    kr[f] = (bf16)v;
    if (f < 64) sk0 += v; else sk1 += v;
  }
  float ks0 = P[(size_t)dp * 68 + 64] + P[gs + (size_t)dp * 68 + 64]
            + P[2 * gs + (size_t)dp * 68 + 64] + P[3 * gs + (size_t)dp * 68 + 64];
  float ks1 = P[(size_t)(64 + dp) * 68 + 64] + P[gs + (size_t)(64 + dp) * 68 + 64]
            + P[2 * gs + (size_t)(64 + dp) * 68 + 64] + P[3 * gs + (size_t)(64 + dp) * 68 + 64];
  ksbuf[(size_t)bh * 136 + dp]      = ks0;
  ksbuf[(size_t)bh * 136 + 64 + dp] = ks1;
  float sks0 = ks0, sks1 = ks1;
#pragma unroll
  for (int o = 1; o < 64; o <<= 1) { sks0 += __shfl_xor(sks0, o); sks1 += __shfl_xor(sks1, o); }
  kr[128] = (bf16)(62.f * sk0);
  kr[129] = (bf16)(62.f * sk1);
#pragma unroll
  for (int f = 130; f < 160; f++) kr[f] = (bf16)0.f;
  if (dp == 0) {
    ksbuf[(size_t)bh * 136 + 128] = sks0;
    ksbuf[(size_t)bh * 136 + 129] = sks1;
  }
}

// ---------------------------------------------------------------------------
// K6: fused attention: q-softmax + z1/z2 -> Aq rows in LDS -> MFMA vs KVT
// ---------------------------------------------------------------------------
#define ASTR 168
__global__ __launch_bounds__(256) void k_attn(const float* __restrict__ QT,
                                              const bf16* __restrict__ KVT,
                                              const float* __restrict__ ksbuf,
                                              bf16* __restrict__ attn) {
  __shared__ __attribute__((aligned(16))) bf16 Abuf[128 * ASTR];
  __shared__ __attribute__((aligned(16))) bf16 Bbuf[64 * ASTR];
  __shared__ float ksl[136];
  const int lc = blockIdx.x;   // 0..15
  const int bh = blockIdx.y;
  const int b = bh >> 4, h = bh & 15;
  const int t = threadIdx.x;

  {
    const bf16* src = KVT + (size_t)bh * 64 * 160;
#pragma unroll
    for (int i = 0; i < 5; i++) {
      const int idx = t + i * 256;
      const int row = idx / 20, ch = idx % 20;
      *(bf16x8*)&Bbuf[row * ASTR + ch * 8] = *(const bf16x8*)(src + row * 160 + ch * 8);
    }
    if (t < 130) ksl[t] = ksbuf[(size_t)bh * 136 + t];
  }
  __syncthreads();

  if (t < 128) {
    const int l = lc * 128 + t;
    const float* qp = QT + ((size_t)bh * 64) * 2048 + l;
    float xv[64];
#pragma unroll
    for (int d = 0; d < 64; d++) xv[d] = qp[(size_t)d * 2048];
    float mx = -1e30f;
#pragma unroll
    for (int d = 0; d < 64; d++) mx = fmaxf(mx, xv[d]);
    float s = 0.f;
#pragma unroll
    for (int d = 0; d < 64; d++) { xv[d] = __expf(xv[d] - mx); s += xv[d]; }
    const float inv = 1.f / s;
    float t0 = 0.f, t1 = 0.f;
#pragma unroll
    for (int d = 0; d < 64; d++) {
      xv[d] *= inv;
      t0 += xv[d] * ksl[d];
      t1 += xv[d] * ksl[64 + d];
    }
    const float SKS0 = ksl[128], SKS1 = ksl[129];
    const float ang = PI2_ * (float)(l + 1) / (float)L_;
    const float sn = __sinf(ang), cs = __cosf(ang);
    const float den1 = sn * t0 + cs * t1;
    const float den2 = sn * (62.f * SKS0 + t0) + cs * (62.f * SKS1 + t1);
    const float z1 = 1.f / fmaxf(den1, EPS_);
    const float z2 = 1.f / fmaxf(den2, EPS_);
    const float zz = z1 + z2;
    const float a0 = zz * sn, a1 = zz * cs;
    bf16* ar = &Abuf[t * ASTR];
#pragma unroll
    for (int g = 0; g < 8; g++) {
      bf16x8 w;
#pragma unroll
      for (int j = 0; j < 8; j++) w[j] = (bf16)(a0 * xv[g * 8 + j]);
      *(bf16x8*)(ar + g * 8) = w;
    }
#pragma unroll
    for (int g = 0; g < 8; g++) {
      bf16x8 w;
#pragma unroll
      for (int j = 0; j < 8; j++) w[j] = (bf16)(a1 * xv[g * 8 + j]);
      *(bf16x8*)(ar + 64 + g * 8) = w;
    }
    bf16x8 wt = {};
    wt[0] = (bf16)(z2 * sn); wt[1] = (bf16)(z2 * cs);
    *(bf16x8*)(ar + 128) = wt;
    bf16x8 zr = {};
    *(bf16x8*)(ar + 136) = zr;
    *(bf16x8*)(ar + 144) = zr;
    *(bf16x8*)(ar + 152) = zr;
  }
  __syncthreads();

  const int wid = t >> 6, lane = t & 63;
  const int quad = lane >> 4, l15 = lane & 15;
  const int wm = wid >> 1, wn = wid & 1;
  floatx4 acc[4][2] = {};
#pragma unroll
  for (int kk = 0; kk < 5; kk++) {
    bf16x8 af[4], bfm[2];
#pragma unroll
    for (int i = 0; i < 4; i++)
      af[i] = *(const bf16x8*)&Abuf[(wm * 64 + i * 16 + l15) * ASTR + kk * 32 + quad * 8];
#pragma unroll
    for (int j = 0; j < 2; j++)
      bfm[j] = *(const bf16x8*)&Bbuf[(wn * 32 + j * 16 + l15) * ASTR + kk * 32 + quad * 8];
#pragma unroll
    for (int i = 0; i < 4; i++)
#pragma unroll
      for (int j = 0; j < 2; j++)
        acc[i][j] = __builtin_amdgcn_mfma_f32_16x16x32_bf16(af[i], bfm[j], acc[i][j], 0, 0, 0);
  }
#pragma unroll
  for (int i = 0; i < 4; i++)
#pragma unroll
    for (int j = 0; j < 2; j++) {
      const int dp = wn * 32 + j * 16 + l15;
#pragma unroll
      for (int r = 0; r < 4; r++) {
        const int l = lc * 128 + wm * 64 + i * 16 + quad * 4 + r;
        attn[((size_t)l * B_ + b) * E_ + h * 64 + dp] = (bf16)acc[i][j][r];
      }
    }
}

// ---------------------------------------------------------------------------
// K7: final projection GEMM: d_out = attnb @ WoT^T + bo (fp32 out)
// ---------------------------------------------------------------------------
__global__ __launch_bounds__(256) void k_gemm_final(const bf16* __restrict__ A,
                                                    const bf16* __restrict__ Bt,
                                                    const float* __restrict__ bias,
                                                    float* __restrict__ C) {
  __shared__ __attribute__((aligned(16))) bf16 As[128 * 32];
  __shared__ __attribute__((aligned(16))) bf16 Bs[128 * 32];
  const int tid  = threadIdx.x;
  const int wid  = tid >> 6;
  const int lane = tid & 63;
  const int quad = lane >> 4;
  const int l15  = lane & 15;
  const int wm   = wid >> 1, wn = wid & 1;
  const int bm   = blockIdx.y, bn = blockIdx.x;

  const bf16* ga0 = A  + (size_t)(bm * 128 + wid * 32 + (lane >> 2)) * E_ + (lane & 3) * 8;
  const bf16* ga1 = ga0 + (size_t)16 * E_;
  const bf16* gb0 = Bt + (size_t)(bn * 128 + wid * 32 + (lane >> 2)) * E_ + (lane & 3) * 8;
  const bf16* gb1 = gb0 + (size_t)16 * E_;
  bf16* la = &As[wid * 1024];
  bf16* lb = &Bs[wid * 1024];

  floatx4 acc[4][4] = {};
  for (int kk = 0; kk < E_; kk += 32) {
    async_cp16(ga0, la);        async_cp16(ga1, la + 512);
    async_cp16(gb0, lb);        async_cp16(gb1, lb + 512);
    ga0 += 32; ga1 += 32; gb0 += 32; gb1 += 32;
    __syncthreads();
    bf16x8 af[4], bfm[4];
#pragma unroll
    for (int i = 0; i < 4; i++)
      af[i] = *(const bf16x8*)&As[(wm * 64 + i * 16 + l15) * 32 + quad * 8];
#pragma unroll
    for (int i = 0; i < 4; i++)
      bfm[i] = *(const bf16x8*)&Bs[(wn * 64 + i * 16 + l15) * 32 + quad * 8];
#pragma unroll
    for (int i = 0; i < 4; i++)
#pragma unroll
      for (int j = 0; j < 4; j++)
        acc[i][j] = __builtin_amdgcn_mfma_f32_16x16x32_bf16(af[i], bfm[j], acc[i][j], 0, 0, 0);
    __syncthreads();
  }
#pragma unroll
  for (int i = 0; i < 4; i++)
#pragma unroll
    for (int j = 0; j < 4; j++) {
      const int col = bn * 128 + wn * 64 + j * 16 + l15;
      const float bv = bias[col];
#pragma unroll
      for (int r = 0; r < 4; r++) {
        const int row = bm * 128 + wm * 64 + i * 16 + quad * 4 + r;
        C[(size_t)row * E_ + col] = acc[i][j][r] + bv;
      }
    }
}

// ---------------------------------------------------------------------------
// Workspace layout (bytes), total 230,232,064 (<= 243,269,632):
//  QT    fp32 [128][64][2048]  @ 0             (67,108,864)
//  KT    fp32 [128][64][2048]  @  67,108,864   (67,108,864)
//  VT    bf16 [128][64][2048]  @ 134,217,728   (33,554,432)
//  Wt    bf16 x4               @ 167,772,160   ( 8,388,608)
//  Xbf   bf16                  @ 176,160,768   (33,554,432) -> attnb overlay
//  kvp   fp32 [4][128][128][68]@ 209,715,200   (17,825,792)
//  KVT   bf16 [128][64][160]   @ 227,540,992   ( 2,621,440)
//  ksbuf fp32 [128][136]       @ 230,162,432   (    69,632)
// ---------------------------------------------------------------------------
extern "C" void kernel_launch(void* const* d_in, const int* in_sizes, int n_in,
                              void* d_out, int out_size, void* d_ws, size_t ws_size,
                              hipStream_t stream) {
  (void)in_sizes; (void)n_in; (void)out_size; (void)ws_size;
  const float* query = (const float*)d_in[0];
  const float* Wq = (const float*)d_in[1];
  const float* bq = (const float*)d_in[2];
  const float* Wk = (const float*)d_in[3];
  const float* bk = (const float*)d_in[4];
  const float* Wv = (const float*)d_in[5];
  const float* bv = (const float*)d_in[6];
  const float* Wo = (const float*)d_in[7];
  const float* bo = (const float*)d_in[8];

  char* ws = (char*)d_ws;
  float* QT   = (float*)(ws + 0);
  float* KT   = (float*)(ws + 67108864);
  bf16*  VT   = (bf16*) (ws + 134217728);
  bf16*  Wt   = (bf16*) (ws + 167772160);
  bf16*  Xbf  = (bf16*) (ws + 176160768);
  bf16*  attnb= (bf16*) (ws + 176160768);
  float* kvp  = (float*)(ws + 209715200);
  bf16*  KVT  = (bf16*) (ws + 227540992);
  float* ksbuf= (float*)(ws + 230162432);

  // 1) X -> bf16
  k_convert_x<<<(M_ * E_) / (256 * 8), 256, 0, stream>>>(query, Xbf);

  // 2) W^T -> bf16 for all four weights
  TArgs ta;
  ta.src[0] = Wq; ta.src[1] = Wk; ta.src[2] = Wv; ta.src[3] = Wo;
  ta.dst[0] = Wt;                       ta.dst[1] = Wt + (size_t)E_ * E_;
  ta.dst[2] = Wt + (size_t)2 * E_ * E_; ta.dst[3] = Wt + (size_t)3 * E_ * E_;
  k_transpose_w<<<dim3(32, 32, 4), dim3(32, 8), 0, stream>>>(ta);

  // 3) QKV GEMM (1D swizzled grid: bn = id&7, z innermost per bm)
  k_gemm_qkv<<<3072, 256, 0, stream>>>(Xbf, Wt, bq, bk, bv, QT, KT, VT);

  // 4) fused k-softmax + features + KV GEMM
  k_kv<<<dim3(4, 128), 256, 0, stream>>>(KT, VT, kvp);

  // 5) consts: KVT + ksbuf
  k_consts<<<128, 64, 0, stream>>>(kvp, KVT, ksbuf);

  // 6) fused attention
  k_attn<<<dim3(16, 128), 256, 0, stream>>>(QT, KVT, ksbuf, attnb);

  // 7) final projection -> d_out
  k_gemm_final<<<dim3(8, M_ / 128), 256, 0, stream>>>(attnb, Wt + (size_t)3 * E_ * E_, bo, (float*)d_out);
}